// Round 10
// baseline (55.056 us; speedup 1.0000x reference)
//
#include <hip/hip_runtime.h>
#include <math.h>

#define N_ 2
#define L_ 2048
#define H_ 8
#define E_ 64
#define D_ 64
#define C_ 128                 // chunk size
#define NC (L_/C_)             // 16
#define ROWSTRIDE (H_*E_)      // 512 floats between consecutive l
#define TEMP 0.125f            // 1/sqrt(64)
#define EPS_F 1e-6f
#define NEG_INF_F (-1e9f)
#define CHUNK_WS (E_*D_ + E_)  // 4160 floats per (n,h,chunk) ws entry
#define NCHUNKS (N_*H_*NC)     // 256
#define TPAD 136               // transposed bf16 tile row stride (shorts)
#define PPAD 72                // pbuf row stride (shorts); 144B, 16B-aligned

typedef __attribute__((ext_vector_type(8))) short short8;   // 8 bf16 in 4 VGPRs
typedef __attribute__((ext_vector_type(4))) float f32x4;

__device__ __forceinline__ short f2bf(float x) {
  unsigned u = __float_as_uint(x);
  u += 0x7fffu + ((u >> 16) & 1u);   // round-to-nearest-even
  return (short)(u >> 16);
}
__device__ __forceinline__ float bf2f(short s) {
  return __uint_as_float(((unsigned)(unsigned short)s) << 16);
}
// tanh(x)+1 = 2/(1+exp(-2x))
__device__ __forceinline__ float tanh1f(float x) {
  float e = __expf(-2.f * x);
  return 2.f * __builtin_amdgcn_rcpf(1.f + e);
}

// Stage [128][64] f32 global tile -> swizzled bf16 LDS tile ([row][64]), f(x,row).
template <typename F>
__device__ __forceinline__ void stage_tile(short* __restrict__ dst,
                                           const float* __restrict__ src, F f) {
  const int t = threadIdx.x;
#pragma unroll
  for (int it = 0; it < 4; ++it) {
    int gi = it * 256 + t;
    int row = gi >> 3, g = gi & 7;
    const float* p = src + row * ROWSTRIDE + g * 8;
    float4 a = *(const float4*)p;
    float4 b = *(const float4*)(p + 4);
    float xs[8] = {a.x, a.y, a.z, a.w, b.x, b.y, b.z, b.w};
    short8 v;
#pragma unroll
    for (int j = 0; j < 8; ++j) v[j] = f2bf(f(xs[j], row));
    *(short8*)(dst + row * 64 + (g ^ (row & 7)) * 8) = v;
  }
}

// Stage V^T: [128][64] f32 rows -> vt[d][s] bf16 [64][TPAD].
__device__ __forceinline__ void stage_vT(short* __restrict__ vt,
                                         const float* __restrict__ Vbase) {
  const int t = threadIdx.x;
  const int d = t & 63, sb = t >> 6;
#pragma unroll
  for (int q = 0; q < 4; ++q) {
    int s0 = sb * 32 + q * 8;
    short8 v;
#pragma unroll
    for (int j = 0; j < 8; ++j) v[j] = f2bf(Vbase[(s0 + j) * ROWSTRIDE + d]);
    *(short8*)(vt + d * TPAD + (s0 >> 3) * 8) = v;
  }
}

// A/B fragment from swizzled row-major bf16 tile.
__device__ __forceinline__ short8 frag_ld(const short* __restrict__ buf,
                                          int rowbase, int hf, int lane) {
  int r = rowbase + (lane & 15);
  int g = (hf * 4 + (lane >> 4)) ^ (r & 7);
  return *(const short8*)(buf + r * 64 + g * 8);
}
// fragment from transposed padded tile [64][TPAD].
__device__ __forceinline__ short8 frag_ldT(const short* __restrict__ buf,
                                           int nbase, int g, int lane) {
  int r = nbase + (lane & 15);
  return *(const short8*)(buf + r * TPAD + g * 8);
}
// A fragment from pbuf [128][PPAD] (64-col half tile).
__device__ __forceinline__ short8 frag_ldP(const short* __restrict__ buf,
                                           int rowbase, int ks, int lane) {
  int r = rowbase + (lane & 15);
  int g = ks * 4 + (lane >> 4);
  return *(const short8*)(buf + r * PPAD + g * 8);
}

// ---------------- Kernel 1: k_pre — deep grid (2688 blocks), three roles -------------
// role A (r<136):   denom partials; band tiles (kb>=qb-1) also produce PV tile (f32)
// role B (136..151): chunk sums (KV^T + ksum)
// role C (152..167): linear-local: tril(Q1K1^T) rowsum + @V tile (f32)
// NOTE: no waves/EU bound; no accumulator arrays passed to functions (rule #20).
extern "C" __global__ void __launch_bounds__(256)
k_pre(const float* __restrict__ Q, const float* __restrict__ K,
      const float* __restrict__ V, const float* __restrict__ mask,
      float* __restrict__ ws, float* __restrict__ part,
      float* __restrict__ pvd, float* __restrict__ pvp,
      float* __restrict__ lvl, float* __restrict__ rsuml) {
  __shared__ short ldsA[9216];   // Q [128][64] -> pbuf [128][PPAD] ; role B: k1T
  __shared__ short ldsB[8192];   // K [128][64]
  __shared__ short ldsC[8704];   // vT [64][TPAD] ; role B: vT
  __shared__ float fmsk[C_];
  const int orig = blockIdx.x;                       // 2688 = 8 * 336
  const int swz = (orig & 7) * 336 + (orig >> 3);    // XCD x owns nh {2x,2x+1}
  const int nh = swz / 168;
  const int r = swz - nh * 168;
  const int h = nh & (H_ - 1), n = nh >> 3;
  const int t = threadIdx.x;
  const int w = t >> 6, lane = t & 63;
  const int col_lo = lane & 15;

  if (r < 136) {
    // ================= role A: denom (+ band PV) =================
    const int p = r;
    int qb = (int)((sqrtf(8.f * p + 1.f) - 1.f) * 0.5f);
    while ((qb + 1) * (qb + 2) / 2 <= p) ++qb;
    while (qb * (qb + 1) / 2 > p) --qb;
    const int kb = p - qb * (qb + 1) / 2;
    const bool diag = (kb == qb), prev = (kb == qb - 1), band = diag || prev;
    const int koff = ((n * L_ + kb * C_) * H_ + h) * E_;

    stage_tile(ldsA, Q + ((n * L_ + qb * C_) * H_ + h) * E_,
               [](float x, int) { return x; });
    stage_tile(ldsB, K + koff, [](float x, int) { return x; });
    if (band) stage_vT(ldsC, V + koff);
    if (t < C_) fmsk[t] = mask[n * L_ + kb * C_ + t];
    __syncthreads();

    short8 afr[2][2];
#pragma unroll
    for (int m = 0; m < 2; ++m)
#pragma unroll
      for (int hf = 0; hf < 2; ++hf)
        afr[m][hf] = frag_ld(ldsA, w * 32 + 16 * m, hf, lane);
    __syncthreads();   // Q reads done; ldsA becomes pbuf

    float rs[2][4] = {};
    f32x4 accPV[2][4];
#pragma unroll
    for (int m = 0; m < 2; ++m)
#pragma unroll
      for (int nn = 0; nn < 4; ++nn) accPV[m][nn] = (f32x4){0.f, 0.f, 0.f, 0.f};

#pragma unroll
    for (int hh = 0; hh < 2; ++hh) {
#pragma unroll
      for (int cc = 0; cc < 4; ++cc) {
        const int ct = hh * 4 + cc;
        short8 b0 = frag_ld(ldsB, 16 * ct, 0, lane);
        short8 b1 = frag_ld(ldsB, 16 * ct, 1, lane);
        const int col = 16 * ct + col_lo;
        const float madd = (fmsk[col] > 0.f) ? 0.f : NEG_INF_F;
#pragma unroll
        for (int m = 0; m < 2; ++m) {
          f32x4 c = (f32x4){0.f, 0.f, 0.f, 0.f};
          c = __builtin_amdgcn_mfma_f32_16x16x32_bf16(afr[m][0], b0, c, 0, 0, 0);
          c = __builtin_amdgcn_mfma_f32_16x16x32_bf16(afr[m][1], b1, c, 0, 0, 0);
          const int rbase = w * 32 + 16 * m + ((lane >> 4) << 2);
#pragma unroll
          for (int reg = 0; reg < 4; ++reg) {
            float x = c[reg] + madd;
            if (diag && col > rbase + reg) x += NEG_INF_F;
            float e = __expf(x * TEMP);
            rs[m][reg] += e;                         // denominator (unbanded)
            if (band) {
              if (prev && col < rbase + reg) e = 0.f;   // band: keep s >= l-128
              ldsA[(rbase + reg) * PPAD + cc * 16 + col_lo] = f2bf(e);
            }
          }
        }
      }
      if (band) {   // PV for s in [64*hh, 64*hh+64); pbuf rows are wave-private
#pragma unroll
        for (int ks = 0; ks < 2; ++ks) {
          short8 ap0 = frag_ldP(ldsA, w * 32, ks, lane);
          short8 ap1 = frag_ldP(ldsA, w * 32 + 16, ks, lane);
#pragma unroll
          for (int nn = 0; nn < 4; ++nn) {
            short8 bv = frag_ldT(ldsC, 16 * nn, 8 * hh + ks * 4 + (lane >> 4), lane);
            accPV[0][nn] = __builtin_amdgcn_mfma_f32_16x16x32_bf16(ap0, bv, accPV[0][nn], 0, 0, 0);
            accPV[1][nn] = __builtin_amdgcn_mfma_f32_16x16x32_bf16(ap1, bv, accPV[1][nn], 0, 0, 0);
          }
        }
      }
    }
    // part write
    float* pout = part + (size_t)(nh * NC + qb) * C_ * 16;
#pragma unroll
    for (int m = 0; m < 2; ++m) {
#pragma unroll
      for (int off = 1; off < 16; off <<= 1)
#pragma unroll
        for (int reg = 0; reg < 4; ++reg) rs[m][reg] += __shfl_xor(rs[m][reg], off);
      if (col_lo == 0) {
        const int rbase = w * 32 + 16 * m + ((lane >> 4) << 2);
#pragma unroll
        for (int reg = 0; reg < 4; ++reg) pout[(rbase + reg) * 16 + kb] = rs[m][reg];
      }
    }
    // band tile write
    if (band) {
      float* outp = (diag ? pvd : pvp) + (size_t)(nh * NC + qb) * (C_ * D_);
#pragma unroll
      for (int m = 0; m < 2; ++m) {
        const int rbase = w * 32 + 16 * m + ((lane >> 4) << 2);
#pragma unroll
        for (int nn = 0; nn < 4; ++nn)
#pragma unroll
          for (int reg = 0; reg < 4; ++reg)
            outp[(rbase + reg) * D_ + 16 * nn + col_lo] = accPV[m][nn][reg];
      }
    }
  } else if (r < 152) {
    // ================= role B: chunk sums =================
    const int c = r - 136;
    const int gbase = ((n * L_ + c * C_) * H_ + h) * E_;
    const int e = t & 63, sb = t >> 6;
    const int mbase = n * L_ + c * C_;
#pragma unroll
    for (int q = 0; q < 4; ++q) {
      int s0 = sb * 32 + q * 8;
      short8 kk, vv;
#pragma unroll
      for (int j = 0; j < 8; ++j) {
        float kx = K[gbase + (s0 + j) * ROWSTRIDE + e];
        kk[j] = f2bf(tanh1f(kx) * mask[mbase + s0 + j]);
        vv[j] = f2bf(V[gbase + (s0 + j) * ROWSTRIDE + e]);
      }
      *(short8*)(ldsA + e * TPAD + (s0 >> 3) * 8) = kk;
      *(short8*)(ldsC + e * TPAD + (s0 >> 3) * 8) = vv;
    }
    __syncthreads();

    f32x4 acc[4];
#pragma unroll
    for (int nn = 0; nn < 4; ++nn) acc[nn] = (f32x4){0.f, 0.f, 0.f, 0.f};
#pragma unroll
    for (int ks = 0; ks < 4; ++ks) {
      short8 a = frag_ldT(ldsC, 16 * w, ks * 4 + (lane >> 4), lane);
#pragma unroll
      for (int nn = 0; nn < 4; ++nn) {
        short8 b = frag_ldT(ldsA, 16 * nn, ks * 4 + (lane >> 4), lane);
        acc[nn] = __builtin_amdgcn_mfma_f32_16x16x32_bf16(a, b, acc[nn], 0, 0, 0);
      }
    }
    float* wsc = ws + (size_t)(nh * NC + c) * CHUNK_WS;
    const int drow = 16 * w + ((lane >> 4) << 2);
#pragma unroll
    for (int nn = 0; nn < 4; ++nn)
#pragma unroll
      for (int reg = 0; reg < 4; ++reg)
        wsc[(16 * nn + col_lo) * D_ + drow + reg] = acc[nn][reg];
    if (t < 64) {
      float s = 0.f;
#pragma unroll
      for (int g = 0; g < 16; ++g) {
        short8 v = *(const short8*)(ldsA + t * TPAD + g * 8);
#pragma unroll
        for (int j = 0; j < 8; ++j) s += bf2f(v[j]);
      }
      wsc[E_ * D_ + t] = s;
    }
  } else {
    // ================= role C: linear-local =================
    const int qb = r - 152;
    const int gbase = ((n * L_ + qb * C_) * H_ + h) * E_;
    const float* mrow = mask + n * L_ + qb * C_;

    stage_tile(ldsA, Q + gbase, [](float x, int) { return tanh1f(x); });
    stage_tile(ldsB, K + gbase,
               [mrow](float x, int row) { return tanh1f(x) * mrow[row]; });
    stage_vT(ldsC, V + gbase);
    __syncthreads();

    short8 afr[2][2];
#pragma unroll
    for (int m = 0; m < 2; ++m)
#pragma unroll
      for (int hf = 0; hf < 2; ++hf)
        afr[m][hf] = frag_ld(ldsA, w * 32 + 16 * m, hf, lane);
    __syncthreads();   // ldsA becomes pbuf

    float rs[2][4] = {};
    f32x4 accPV[2][4];
#pragma unroll
    for (int m = 0; m < 2; ++m)
#pragma unroll
      for (int nn = 0; nn < 4; ++nn) accPV[m][nn] = (f32x4){0.f, 0.f, 0.f, 0.f};

#pragma unroll
    for (int hh = 0; hh < 2; ++hh) {
#pragma unroll
      for (int cc = 0; cc < 4; ++cc) {
        const int ct = hh * 4 + cc;
        short8 b0 = frag_ld(ldsB, 16 * ct, 0, lane);
        short8 b1 = frag_ld(ldsB, 16 * ct, 1, lane);
        const int col = 16 * ct + col_lo;
#pragma unroll
        for (int m = 0; m < 2; ++m) {
          f32x4 c = (f32x4){0.f, 0.f, 0.f, 0.f};
          c = __builtin_amdgcn_mfma_f32_16x16x32_bf16(afr[m][0], b0, c, 0, 0, 0);
          c = __builtin_amdgcn_mfma_f32_16x16x32_bf16(afr[m][1], b1, c, 0, 0, 0);
          const int rbase = w * 32 + 16 * m + ((lane >> 4) << 2);
#pragma unroll
          for (int reg = 0; reg < 4; ++reg) {
            float v = c[reg];
            if (col <= rbase + reg) rs[m][reg] += v;   // tril rowsum
            else v = 0.f;                              // tril mask
            ldsA[(rbase + reg) * PPAD + cc * 16 + col_lo] = f2bf(v);
          }
        }
      }
#pragma unroll
      for (int ks = 0; ks < 2; ++ks) {
        short8 ap0 = frag_ldP(ldsA, w * 32, ks, lane);
        short8 ap1 = frag_ldP(ldsA, w * 32 + 16, ks, lane);
#pragma unroll
        for (int nn = 0; nn < 4; ++nn) {
          short8 bv = frag_ldT(ldsC, 16 * nn, 8 * hh + ks * 4 + (lane >> 4), lane);
          accPV[0][nn] = __builtin_amdgcn_mfma_f32_16x16x32_bf16(ap0, bv, accPV[0][nn], 0, 0, 0);
          accPV[1][nn] = __builtin_amdgcn_mfma_f32_16x16x32_bf16(ap1, bv, accPV[1][nn], 0, 0, 0);
        }
      }
    }
    float* rout = rsuml + (size_t)(nh * NC + qb) * C_;
#pragma unroll
    for (int m = 0; m < 2; ++m) {
#pragma unroll
      for (int off = 1; off < 16; off <<= 1)
#pragma unroll
        for (int reg = 0; reg < 4; ++reg) rs[m][reg] += __shfl_xor(rs[m][reg], off);
      if (col_lo == 0) {
        const int rbase = w * 32 + 16 * m + ((lane >> 4) << 2);
#pragma unroll
        for (int reg = 0; reg < 4; ++reg) rout[rbase + reg] = rs[m][reg];
      }
    }
    float* outp = lvl + (size_t)(nh * NC + qb) * (C_ * D_);
#pragma unroll
    for (int m = 0; m < 2; ++m) {
      const int rbase = w * 32 + 16 * m + ((lane >> 4) << 2);
#pragma unroll
      for (int nn = 0; nn < 4; ++nn)
#pragma unroll
        for (int reg = 0; reg < 4; ++reg)
          outp[(rbase + reg) * D_ + 16 * nn + col_lo] = accPV[m][nn][reg];
    }
  }
}

// ---------------- Kernel 2: exclusive prefix scan, element-parallel ------------------
extern "C" __global__ void __launch_bounds__(256)
k_scan(float* __restrict__ ws) {
  const int bid = blockIdx.x;                        // 272 = 8 * 34
  const int swz = (bid & 7) * 34 + (bid >> 3);
  const int nh = swz / 17, seg = swz - nh * 17;
  const int idx = seg * 256 + threadIdx.x;
  if (idx >= CHUNK_WS) return;
  float* base = ws + (size_t)nh * NC * CHUNK_WS + idx;
  float v[NC];
#pragma unroll
  for (int c = 0; c < NC; ++c) v[c] = base[(size_t)c * CHUNK_WS];
  float acc = 0.f;
#pragma unroll
  for (int c = 0; c < NC; ++c) {
    base[(size_t)c * CHUNK_WS] = acc;
    acc += v[c];
  }
}

// ---------------- Kernel 3: combine — Q1@S_start + normalize + blend -----------------
extern "C" __global__ void __launch_bounds__(256)
k_comb(const float* __restrict__ Q, const float* __restrict__ blend,
       const float* __restrict__ ws, const float* __restrict__ part,
       const float* __restrict__ pvd, const float* __restrict__ pvp,
       const float* __restrict__ lvl, const float* __restrict__ rsuml,
       float* __restrict__ out) {
  __shared__ short kv[64 * TPAD];    // S^T
  __shared__ float zlds[64];
  __shared__ float dinv[64];
  __shared__ float ksum[E_];

  const int orig = blockIdx.x;                      // 512 = 8 * 64
  const int swz = (orig & 7) * 64 + (orig >> 3);
  const int rh = swz & 1, qb = (swz >> 1) & (NC - 1), nh = swz >> 5;
  const int h = nh & (H_ - 1), n = nh >> 3;
  const int t = threadIdx.x;
  const int w = t >> 6, lane = t & 63;
  const int rowbase = w * 16;
  const int col_lo = lane & 15;
  const int rb = rowbase + ((lane >> 4) << 2);
  const int rtile0 = rh * 64 + rb;
  const int qgbase = ((n * L_ + qb * C_ + rh * 64) * H_ + h) * E_;
  const float* wsc = ws + (size_t)(nh * NC + qb) * CHUNK_WS;
  const float bl = blend[0];
  const float ob = 1.f - bl;
  const int d = t & 63;
  const size_t tb = (size_t)(nh * NC + qb) * (C_ * D_);

  // ---- seg1: all staging / prefetch ----
  short8 af1[2];
  {
    const float* qp = Q + qgbase + (rowbase + (lane & 15)) * ROWSTRIDE;
#pragma unroll
    for (int kh = 0; kh < 2; ++kh) {
      int c0 = (kh * 4 + (lane >> 4)) * 8;
      float4 a = *(const float4*)(qp + c0);
      float4 b = *(const float4*)(qp + c0 + 4);
      float xs[8] = {a.x, a.y, a.z, a.w, b.x, b.y, b.z, b.w};
#pragma unroll
      for (int j = 0; j < 8; ++j) af1[kh][j] = f2bf(tanh1f(xs[j]));
    }
  }
  {  // S^T into kv
    int eb = t >> 6;
#pragma unroll
    for (int q = 0; q < 2; ++q) {
      int e0 = eb * 16 + q * 8;
      short8 v;
#pragma unroll
      for (int j = 0; j < 8; ++j) v[j] = f2bf(wsc[(e0 + j) * D_ + d]);
      *(short8*)(kv + d * TPAD + (e0 >> 3) * 8) = v;
    }
  }
  if (t < 64) {
    ksum[t] = wsc[E_ * D_ + t];
    const float* pb = part + ((size_t)(nh * NC + qb) * C_ + rh * 64 + t) * 16;
    float4 a = *(const float4*)pb, b = *(const float4*)(pb + 4);
    float4 c = *(const float4*)(pb + 8), d4 = *(const float4*)(pb + 12);
    float vv[16] = {a.x, a.y, a.z, a.w, b.x, b.y, b.z, b.w,
                    c.x, c.y, c.z, c.w, d4.x, d4.y, d4.z, d4.w};
    float s = 0.f;
#pragma unroll
    for (int j = 0; j < 16; ++j) s += (j <= qb) ? vv[j] : 0.f;
    dinv[t] = 1.f / s;
  }
  float rsv[4];
#pragma unroll
  for (int reg = 0; reg < 4; ++reg)
    rsv[reg] = rsuml[(size_t)(nh * NC + qb) * C_ + rtile0 + reg];
  float lvv[4][4], pvv[4][4];
#pragma unroll
  for (int nn = 0; nn < 4; ++nn)
#pragma unroll
    for (int reg = 0; reg < 4; ++reg) {
      size_t a = tb + (size_t)(rtile0 + reg) * D_ + 16 * nn + col_lo;
      lvv[nn][reg] = lvl[a];
      float pd = pvd[a];
      pvv[nn][reg] = (qb > 0) ? pd + pvp[a] : pd;
    }
  __syncthreads();   // the only barrier

  // ---- zpart = Q1 . Ksum_start ----
  {
    float zz = 0.f;
#pragma unroll
    for (int kh = 0; kh < 2; ++kh) {
      int cb = (kh * 4 + (lane >> 4)) * 8;
#pragma unroll
      for (int j = 0; j < 8; ++j) zz += bf2f(af1[kh][j]) * ksum[cb + j];
    }
    zz += __shfl_xor(zz, 16);
    zz += __shfl_xor(zz, 32);
    if (lane < 16) zlds[rowbase + lane] = zz;
  }
  // ---- accL = Q1 @ S_start ----
  f32x4 accL[4];
#pragma unroll
  for (int nn = 0; nn < 4; ++nn) accL[nn] = (f32x4){0.f, 0.f, 0.f, 0.f};
#pragma unroll
  for (int ks = 0; ks < 2; ++ks) {
    short8 bf[4];
#pragma unroll
    for (int nn = 0; nn < 4; ++nn)
      bf[nn] = frag_ldT(kv, 16 * nn, ks * 4 + (lane >> 4), lane);
#pragma unroll
    for (int nn = 0; nn < 4; ++nn)
      accL[nn] = __builtin_amdgcn_mfma_f32_16x16x32_bf16(af1[ks], bf[nn], accL[nn], 0, 0, 0);
  }

  // ---- epilogue: out = ob*z*(Q1@S + LV_local) + bl*dinv*(PV_diag + PV_prev) ----
  float zrf[4], sdv[4];
#pragma unroll
  for (int reg = 0; reg < 4; ++reg) {
    zrf[reg] = ob / (zlds[rb + reg] + rsv[reg] + EPS_F);
    sdv[reg] = bl * dinv[rb + reg];
  }
#pragma unroll
  for (int nn = 0; nn < 4; ++nn)
#pragma unroll
    for (int reg = 0; reg < 4; ++reg)
      out[qgbase + (rb + reg) * ROWSTRIDE + 16 * nn + col_lo] =
          zrf[reg] * (accL[nn][reg] + lvv[nn][reg]) + sdv[reg] * pvv[nn][reg];
}

extern "C" void kernel_launch(void* const* d_in, const int* in_sizes, int n_in,
                              void* d_out, int out_size, void* d_ws, size_t ws_size,
                              hipStream_t stream) {
  (void)in_sizes; (void)n_in; (void)out_size; (void)ws_size;
  const float* Q = (const float*)d_in[0];
  const float* K = (const float*)d_in[1];
  const float* V = (const float*)d_in[2];
  const float* mask = (const float*)d_in[3];
  const float* blend = (const float*)d_in[4];
  float* out = (float*)d_out;
  float* ws = (float*)d_ws;
  // layout (floats): chunk state | part | pv_diag | pv_prev | lv_local | rsum  (~12.6MB)
  float* part  = ws + (size_t)NCHUNKS * CHUNK_WS;
  float* pvd   = part + (size_t)NCHUNKS * C_ * 16;
  float* pvp   = pvd + (size_t)NCHUNKS * C_ * D_;
  float* lvl   = pvp + (size_t)NCHUNKS * C_ * D_;
  float* rsuml = lvl + (size_t)NCHUNKS * C_ * D_;

  k_pre<<<dim3(2688), dim3(256), 0, stream>>>(Q, K, V, mask, ws, part, pvd, pvp, lvl, rsuml);
  k_scan<<<dim3(272), dim3(256), 0, stream>>>(ws);
  k_comb<<<dim3(512), dim3(256), 0, stream>>>(Q, blend, ws, part, pvd, pvp, lvl, rsuml, out);
}